// Round 3
// baseline (748.649 us; speedup 1.0000x reference)
//
#include <hip/hip_runtime.h>
#include <math.h>

#define DF 768      // feature dim
#define NN 64       // nodes
#define DN 832      // batch row stride (D + N)
#define LDH 776     // h row-major LDS row stride (halves), pad breaks bank conflicts
#define LDT 72      // hpT / attn LDS row stride (halves)
#define NEG_SLOPE 0.2f

typedef _Float16 f16;
typedef __attribute__((ext_vector_type(4))) _Float16 f16x4;
typedef __attribute__((ext_vector_type(8))) _Float16 f16x8;
typedef __attribute__((ext_vector_type(4))) float f32x4;

__device__ __forceinline__ float tanh_fast(float x) {
  return 1.0f - 2.0f / (__expf(2.0f * x) + 1.0f);
}

// ---------- prep: transpose w (768x768 fp32) -> wT[o][k] f16 ----------
__global__ void prep_wT(const float* __restrict__ w, f16* __restrict__ wT) {
  __shared__ float tile[32][33];
  int bx = blockIdx.x % 24;   // o tile
  int by = blockIdx.x / 24;   // k tile
  int tx = threadIdx.x & 31;
  int ty = threadIdx.x >> 5;  // 0..7
#pragma unroll
  for (int rr = 0; rr < 4; ++rr)
    tile[ty + rr * 8][tx] = w[(size_t)(by * 32 + ty + rr * 8) * DF + bx * 32 + tx];
  __syncthreads();
#pragma unroll
  for (int rr = 0; rr < 4; ++rr)
    wT[(size_t)(bx * 32 + ty + rr * 8) * DF + by * 32 + tx] = (f16)tile[tx][ty + rr * 8];
}

// ---------- prep: mlp_w fp32 -> f16 ----------
__global__ void prep_mlp(const float* __restrict__ mw, f16* __restrict__ mwh) {
  int i = blockIdx.x * 256 + threadIdx.x;
  mwh[i] = (f16)mw[i];
}

// ---------- fused 2-layer GAT: one workgroup (1024 thr, 16 waves) per batch item ----------
// R2 lesson: at 512 thr the compiler pinned VGPRs to 128 regardless of
// __launch_bounds__, and the 4x6 accumulator tile (~190 regs live) spilled
// ~2 KB/thread inside the K-loop -> 1 GB/dispatch scratch traffic
// (WRITE_SIZE 523 MB observed). Fix: 16 waves x (64x48) tiles so the live
// set (acc 48 + bfr/bnx 24 + af 16 ~= 88) fits the 128-VGPR cap that
// 1024-thr blocks impose structurally (4 waves/SIMD x 128 = full file).
__global__ __launch_bounds__(1024) void gat_fused(
    const float* __restrict__ batch,
    const f16* __restrict__ wT,          // (768 x 768), wT[o][k] = w[k][o]
    const float* __restrict__ a_src,
    const float* __restrict__ a_dst,
    const float* __restrict__ gat_bias,
    f16* __restrict__ cneighW)           // (512 x 768) l2normed h[:,0]
{
  // Hbuf doubles as: h row-major (64 x LDH) and hpT (768 x LDT)
  __shared__ __align__(16) f16 Hbuf[DF * LDT];   // 110592 B
  __shared__ __align__(16) f16 attnB[NN * LDT];  // 9216 B
  __shared__ float asrcL[DF], adstL[DF], biasL[DF];
  __shared__ float srcv[NN], dstv[NN];
  __shared__ float redS[16 * NN], redD[16 * NN];
  __shared__ unsigned long long maskRow[NN];
  __shared__ float attn0[NN];
  __shared__ float h2row[DF];
  __shared__ float ssqred[16];

  const int tid  = threadIdx.x;
  const int lane = tid & 63;
  const int wv   = tid >> 6;     // wave 0..15
  const int l16  = lane & 15;
  const int quad = lane >> 4;    // 0..3
  const int b    = blockIdx.x;
  const int cb   = wv * 48;      // this wave's column base (16 waves x 48 = 768)

  const float* bb = batch + (size_t)b * (NN * DN);

  // params -> LDS
  for (int i = tid; i < DF; i += 1024) {
    asrcL[i] = a_src[i];
    adstL[i] = a_dst[i];
    biasL[i] = gat_bias[i];
  }
  // stage h0 = features (fp32 -> f16), row-major, float4-vectorized
  for (int i = tid; i < NN * (DF / 4); i += 1024) {
    int r = i / (DF / 4), c4 = i - r * (DF / 4);
    float4 v = *(const float4*)&bb[r * DN + c4 * 4];
    f16x4 h4 = {(f16)v.x, (f16)v.y, (f16)v.z, (f16)v.w};
    *(f16x4*)&Hbuf[r * LDH + c4 * 4] = h4;
  }
  // adjacency mask via ballot: wave wv builds rows 4*wv..4*wv+3
#pragma unroll
  for (int r = 0; r < 4; ++r) {
    int n = wv * 4 + r;
    float av = bb[n * DN + DF + lane];
    unsigned long long m = __ballot(av != 0.0f);
    if (lane == 0) maskRow[n] = m | (1ULL << n);   // eye
  }
  __syncthreads();

  for (int layer = 0; layer < 2; ++layer) {
    // ================= GEMM1: hp = h @ w =================
    f32x4 acc[4][3];
#pragma unroll
    for (int rt = 0; rt < 4; ++rt)
#pragma unroll
      for (int ct = 0; ct < 3; ++ct)
        acc[rt][ct] = (f32x4){0.f, 0.f, 0.f, 0.f};

    // B-fragment prefetch pipeline (global, L2-hot)
    f16x8 bfr[3], bnx[3];
#pragma unroll
    for (int ct = 0; ct < 3; ++ct)
      bfr[ct] = *(const f16x8*)&wT[(size_t)(cb + ct * 16 + l16) * DF + quad * 8];

    for (int k0 = 0; k0 < DF; k0 += 32) {
      f16x8 af[4];
#pragma unroll
      for (int rt = 0; rt < 4; ++rt)
        af[rt] = *(const f16x8*)&Hbuf[(rt * 16 + l16) * LDH + k0 + quad * 8];
      if (k0 + 32 < DF) {
#pragma unroll
        for (int ct = 0; ct < 3; ++ct)
          bnx[ct] = *(const f16x8*)&wT[(size_t)(cb + ct * 16 + l16) * DF + (k0 + 32) + quad * 8];
      }
#pragma unroll
      for (int ct = 0; ct < 3; ++ct)
#pragma unroll
        for (int rt = 0; rt < 4; ++rt)
          acc[rt][ct] = __builtin_amdgcn_mfma_f32_16x16x32_f16(af[rt], bfr[ct], acc[rt][ct], 0, 0, 0);
#pragma unroll
      for (int ct = 0; ct < 3; ++ct) bfr[ct] = bnx[ct];
    }
    __syncthreads();   // all h reads done

    // write hp transposed: hpT[o][m]; C layout row=rt*16+quad*4+i, col=cb+ct*16+l16
    // rows for fixed (rt,quad) are 4 consecutive -> f16x4 vector LDS write
#pragma unroll
    for (int rt = 0; rt < 4; ++rt)
#pragma unroll
      for (int ct = 0; ct < 3; ++ct) {
        int row0 = rt * 16 + quad * 4;
        int col  = cb + ct * 16 + l16;
        f16x4 h4 = {(f16)acc[rt][ct][0], (f16)acc[rt][ct][1],
                    (f16)acc[rt][ct][2], (f16)acc[rt][ct][3]};
        *(f16x4*)&Hbuf[col * LDT + row0] = h4;
      }
    __syncthreads();

    // ================= src/dst: th = tanh(hp), dot with a_src/a_dst =================
    {
      float s = 0.f, d = 0.f;
      int m = lane;
      int o0 = wv * 48;
      for (int o = o0; o < o0 + 48; ++o) {
        float t = tanh_fast((float)Hbuf[o * LDT + m]);
        s += t * asrcL[o];
        d += t * adstL[o];
      }
      redS[wv * 64 + m] = s;
      redD[wv * 64 + m] = d;
    }
    __syncthreads();
    if (tid < 64) {
      float s = 0.f, d = 0.f;
#pragma unroll
      for (int q = 0; q < 16; ++q) { s += redS[q * 64 + tid]; d += redD[q * 64 + tid]; }
      srcv[tid] = s;
      dstv[tid] = d;
    }
    __syncthreads();

    if (layer == 0) {
      // ---- full attention: wave wv does rows 4*wv..4*wv+3, lane = neighbor m ----
#pragma unroll
      for (int r = 0; r < 4; ++r) {
        int n = wv * 4 + r;
        float logit = srcv[n] + dstv[lane];
        logit = logit >= 0.f ? logit : NEG_SLOPE * logit;
        bool ok = (maskRow[n] >> lane) & 1ULL;
        float v = ok ? logit : -1e30f;
        float mx = v;
#pragma unroll
        for (int off = 32; off > 0; off >>= 1) mx = fmaxf(mx, __shfl_xor(mx, off, 64));
        float e = ok ? __expf(v - mx) : 0.f;
        float sm = e;
#pragma unroll
        for (int off = 32; off > 0; off >>= 1) sm += __shfl_xor(sm, off, 64);
        attnB[n * LDT + lane] = (f16)(e / sm);
      }
      __syncthreads();

      // ---- GEMM2: h_new = attn @ hp  (A=attnB row-major, B=hpT) ----
      f32x4 acc2[4][3];
#pragma unroll
      for (int rt = 0; rt < 4; ++rt)
#pragma unroll
        for (int ct = 0; ct < 3; ++ct)
          acc2[rt][ct] = (f32x4){0.f, 0.f, 0.f, 0.f};
#pragma unroll
      for (int k0 = 0; k0 < NN; k0 += 32) {
        f16x8 af[4];
#pragma unroll
        for (int rt = 0; rt < 4; ++rt)
          af[rt] = *(const f16x8*)&attnB[(rt * 16 + l16) * LDT + k0 + quad * 8];
#pragma unroll
        for (int ct = 0; ct < 3; ++ct) {
          f16x8 bf = *(const f16x8*)&Hbuf[(cb + ct * 16 + l16) * LDT + k0 + quad * 8];
#pragma unroll
          for (int rt = 0; rt < 4; ++rt)
            acc2[rt][ct] = __builtin_amdgcn_mfma_f32_16x16x32_f16(af[rt], bf, acc2[rt][ct], 0, 0, 0);
        }
      }
      __syncthreads();  // all hpT reads done before overwriting Hbuf
      // h_new (+bias) -> Hbuf row-major (next layer's h)
#pragma unroll
      for (int rt = 0; rt < 4; ++rt)
#pragma unroll
        for (int ct = 0; ct < 3; ++ct)
#pragma unroll
          for (int i = 0; i < 4; ++i) {
            int row = rt * 16 + quad * 4 + i;
            int col = cb + ct * 16 + l16;
            Hbuf[row * LDH + col] = (f16)(acc2[rt][ct][i] + biasL[col]);
          }
      __syncthreads();
    } else {
      // ---- layer 2: only row 0 of h_new is ever used ----
      if (wv == 0) {
        float logit = srcv[0] + dstv[lane];
        logit = logit >= 0.f ? logit : NEG_SLOPE * logit;
        bool ok = (maskRow[0] >> lane) & 1ULL;
        float v = ok ? logit : -1e30f;
        float mx = v;
#pragma unroll
        for (int off = 32; off > 0; off >>= 1) mx = fmaxf(mx, __shfl_xor(mx, off, 64));
        float e = ok ? __expf(v - mx) : 0.f;
        float sm = e;
#pragma unroll
        for (int off = 32; off > 0; off >>= 1) sm += __shfl_xor(sm, off, 64);
        attn0[lane] = e / sm;   // keep fp32
      }
      __syncthreads();
      // h2_0[o] = bias[o] + sum_m attn0[m] * hpT[o][m]  (row o is 64 contiguous halves)
      if (tid < DF) {
        const int o = tid;
        const f16* rowp = &Hbuf[o * LDT];
        float a = biasL[o];
#pragma unroll
        for (int j = 0; j < 8; ++j) {
          f16x8 v = *(const f16x8*)&rowp[j * 8];
#pragma unroll
          for (int e = 0; e < 8; ++e) a += attn0[j * 8 + e] * (float)v[e];
        }
        h2row[o] = a;
      }
      __syncthreads();
      // l2norm of h2_0 -> cneighW
      float p = (tid < DF) ? h2row[tid] * h2row[tid] : 0.f;
#pragma unroll
      for (int off = 32; off > 0; off >>= 1) p += __shfl_xor(p, off, 64);
      if (lane == 0) ssqred[wv] = p;
      __syncthreads();
      if (tid == 0) {
        float ss = 0.f;
#pragma unroll
        for (int q = 0; q < 16; ++q) ss += ssqred[q];
        ssqred[0] = 1.0f / fmaxf(sqrtf(ss), 1e-12f);
      }
      __syncthreads();
      float scale = ssqred[0];
      if (tid < DF)
        cneighW[(size_t)b * DF + tid] = (f16)(h2row[tid] * scale);
    }
  }
}

// ---------- final: out = [center | cneigh] @ mlp_w.T + mlp_b, then row l2norm ----------
__global__ __launch_bounds__(512, 2) void final_mlp(
    const float* __restrict__ batch,
    const f16* __restrict__ cneighW,
    const f16* __restrict__ mwh,         // (768 x 1536) row-major (d, j)
    const float* __restrict__ mlp_b,
    float* __restrict__ out)
{
  __shared__ f16 Abuf[16 * LDT];   // 16 batch rows x 64-k chunk
  __shared__ float nrm[16];
  const int tid  = threadIdx.x;
  const int lane = tid & 63;
  const int wv   = tid >> 6;
  const int l16  = lane & 15;
  const int quad = lane >> 4;
  const int b0   = blockIdx.x * 16;
  const int cb   = wv * 96;

  f32x4 acc[6];
#pragma unroll
  for (int ct = 0; ct < 6; ++ct) acc[ct] = (f32x4){0.f, 0.f, 0.f, 0.f};

  for (int k0 = 0; k0 < 2 * DF; k0 += 64) {
    __syncthreads();
    // stage A chunk: 16 rows x 64 k (center fp32 or cneigh f16)
    for (int i = tid; i < 16 * 64; i += 512) {
      int r = i >> 6, c = i & 63;
      int j = k0 + c;
      float v;
      if (j < DF) v = batch[(size_t)(b0 + r) * (NN * DN) + j];        // node-0 features
      else        v = (float)cneighW[(size_t)(b0 + r) * DF + (j - DF)];
      Abuf[r * LDT + c] = (f16)v;
    }
    __syncthreads();
#pragma unroll
    for (int ks = 0; ks < 64; ks += 32) {
      f16x8 af = *(const f16x8*)&Abuf[l16 * LDT + ks + quad * 8];
#pragma unroll
      for (int ct = 0; ct < 6; ++ct) {
        f16x8 bf = *(const f16x8*)&mwh[(size_t)(cb + ct * 16 + l16) * (2 * DF) + k0 + ks + quad * 8];
        acc[ct] = __builtin_amdgcn_mfma_f32_16x16x32_f16(af, bf, acc[ct], 0, 0, 0);
      }
    }
  }
  if (tid < 16) nrm[tid] = 0.f;
  __syncthreads();
  float vals[6][4];
  float part[4] = {0.f, 0.f, 0.f, 0.f};
#pragma unroll
  for (int ct = 0; ct < 6; ++ct) {
    float bv = mlp_b[cb + ct * 16 + l16];
#pragma unroll
    for (int i = 0; i < 4; ++i) {
      float v = acc[ct][i] + bv;
      vals[ct][i] = v;
      part[i] += v * v;
    }
  }
#pragma unroll
  for (int i = 0; i < 4; ++i) {
    float p = part[i];
    p += __shfl_xor(p, 1, 64);
    p += __shfl_xor(p, 2, 64);
    p += __shfl_xor(p, 4, 64);
    p += __shfl_xor(p, 8, 64);
    if (l16 == 0) atomicAdd(&nrm[quad * 4 + i], p);
  }
  __syncthreads();
  float sc[4];
#pragma unroll
  for (int i = 0; i < 4; ++i) sc[i] = 1.0f / fmaxf(sqrtf(nrm[quad * 4 + i]), 1e-12f);
#pragma unroll
  for (int ct = 0; ct < 6; ++ct)
#pragma unroll
    for (int i = 0; i < 4; ++i) {
      int row = quad * 4 + i;
      int col = cb + ct * 16 + l16;
      out[(size_t)(b0 + row) * DF + col] = vals[ct][i] * sc[i];
    }
}

extern "C" void kernel_launch(void* const* d_in, const int* in_sizes, int n_in,
                              void* d_out, int out_size, void* d_ws, size_t ws_size,
                              hipStream_t stream) {
  const float* batch    = (const float*)d_in[0];  // (512, 64, 832)
  const float* w        = (const float*)d_in[1];  // (1, 768, 768)
  const float* a_src    = (const float*)d_in[2];  // (1, 768, 1)
  const float* a_dst    = (const float*)d_in[3];  // (1, 768, 1)
  const float* gat_bias = (const float*)d_in[4];  // (768,)
  const float* mlp_w    = (const float*)d_in[5];  // (768, 1536)
  const float* mlp_b    = (const float*)d_in[6];  // (768,)
  float* out = (float*)d_out;

  // workspace layout (f16): wT 768x768 | mlp_w 768x1536 | cneigh 512x768
  f16* wT      = (f16*)d_ws;
  f16* mwh     = wT + (size_t)DF * DF;
  f16* cneighW = mwh + (size_t)DF * 2 * DF;

  prep_wT<<<dim3(24 * 24), dim3(256), 0, stream>>>(w, wT);
  prep_mlp<<<dim3((DF * 2 * DF) / 256), dim3(256), 0, stream>>>(mlp_w, mwh);
  gat_fused<<<dim3(512), dim3(1024), 0, stream>>>(batch, wT, a_src, a_dst, gat_bias, cneighW);
  final_mlp<<<dim3(32), dim3(512), 0, stream>>>(batch, cneighW, mwh, mlp_b, out);
}

// Round 4
// 454.161 us; speedup vs baseline: 1.6484x; 1.6484x over previous
//
#include <hip/hip_runtime.h>
#include <math.h>

#define DF 768      // feature dim
#define NN 64       // nodes
#define DN 832      // batch row stride (D + N)
#define LDH 776     // h row-major LDS row stride (halves), pad breaks bank conflicts
#define LDT 72      // hpT / attn LDS row stride (halves)
#define NEG_SLOPE 0.2f

typedef _Float16 f16;
typedef __attribute__((ext_vector_type(4))) _Float16 f16x4;
typedef __attribute__((ext_vector_type(8))) _Float16 f16x8;
typedef __attribute__((ext_vector_type(4))) float f32x4;

__device__ __forceinline__ float tanh_fast(float x) {
  return 1.0f - 2.0f / (__expf(2.0f * x) + 1.0f);
}

// ---------- prep: transpose w (768x768 fp32) -> wT[o][k] f16 ----------
__global__ void prep_wT(const float* __restrict__ w, f16* __restrict__ wT) {
  __shared__ float tile[32][33];
  int bx = blockIdx.x % 24;   // o tile
  int by = blockIdx.x / 24;   // k tile
  int tx = threadIdx.x & 31;
  int ty = threadIdx.x >> 5;  // 0..7
#pragma unroll
  for (int rr = 0; rr < 4; ++rr)
    tile[ty + rr * 8][tx] = w[(size_t)(by * 32 + ty + rr * 8) * DF + bx * 32 + tx];
  __syncthreads();
#pragma unroll
  for (int rr = 0; rr < 4; ++rr)
    wT[(size_t)(bx * 32 + ty + rr * 8) * DF + by * 32 + tx] = (f16)tile[tx][ty + rr * 8];
}

// ---------- prep: mlp_w fp32 -> f16 ----------
__global__ void prep_mlp(const float* __restrict__ mw, f16* __restrict__ mwh) {
  int i = blockIdx.x * 256 + threadIdx.x;
  mwh[i] = (f16)mw[i];
}

// ---------- fused 2-layer GAT: one workgroup (1024 thr, 16 waves) per batch item ----------
// R3 lesson: WRITE_SIZE surplus == 512WG x 1024thr x 1088B exactly -> true
// scratch spill. gfx950 splits the unified file arch/acc; at 1024-thr WGs
// the compiler granted ~64 arch VGPRs and the GEMM1 arch live set
// (af 16 + bfr/bnx 24 + addressing + unroll hoisting) overflowed.
// Fix: no bnx prefetch, unroll(disable) on the K-loop, hoisted base ptr.
// Arch live ~48 regs; latency hidden by 4 waves/SIMD TLP (12 MFMA/iter x
// 4 waves ~= 233 cyc vs ~200 cyc L2 latency).
__global__ __launch_bounds__(1024, 4) void gat_fused(
    const float* __restrict__ batch,
    const f16* __restrict__ wT,          // (768 x 768), wT[o][k] = w[k][o]
    const float* __restrict__ a_src,
    const float* __restrict__ a_dst,
    const float* __restrict__ gat_bias,
    f16* __restrict__ cneighW)           // (512 x 768) l2normed h[:,0]
{
  // Hbuf doubles as: h row-major (64 x LDH) and hpT (768 x LDT)
  __shared__ __align__(16) f16 Hbuf[DF * LDT];   // 110592 B
  __shared__ __align__(16) f16 attnB[NN * LDT];  // 9216 B
  __shared__ float asrcL[DF], adstL[DF], biasL[DF];
  __shared__ float srcv[NN], dstv[NN];
  __shared__ float redS[16 * NN], redD[16 * NN];
  __shared__ unsigned long long maskRow[NN];
  __shared__ float attn0[NN];
  __shared__ float h2row[DF];
  __shared__ float ssqred[16];

  const int tid  = threadIdx.x;
  const int lane = tid & 63;
  const int wv   = tid >> 6;     // wave 0..15
  const int l16  = lane & 15;
  const int quad = lane >> 4;    // 0..3
  const int b    = blockIdx.x;
  const int cb   = wv * 48;      // this wave's column base (16 waves x 48 = 768)

  const float* bb = batch + (size_t)b * (NN * DN);

  // params -> LDS
  for (int i = tid; i < DF; i += 1024) {
    asrcL[i] = a_src[i];
    adstL[i] = a_dst[i];
    biasL[i] = gat_bias[i];
  }
  // stage h0 = features (fp32 -> f16), row-major, float4-vectorized
  for (int i = tid; i < NN * (DF / 4); i += 1024) {
    int r = i / (DF / 4), c4 = i - r * (DF / 4);
    float4 v = *(const float4*)&bb[r * DN + c4 * 4];
    f16x4 h4 = {(f16)v.x, (f16)v.y, (f16)v.z, (f16)v.w};
    *(f16x4*)&Hbuf[r * LDH + c4 * 4] = h4;
  }
  // adjacency mask via ballot: wave wv builds rows 4*wv..4*wv+3
#pragma unroll
  for (int r = 0; r < 4; ++r) {
    int n = wv * 4 + r;
    float av = bb[n * DN + DF + lane];
    unsigned long long m = __ballot(av != 0.0f);
    if (lane == 0) maskRow[n] = m | (1ULL << n);   // eye
  }
  __syncthreads();

  // per-wave wT base: columns cb+ct*16+l16, k offset quad*8
  const f16* wp = wT + (size_t)(cb + l16) * DF + quad * 8;

  for (int layer = 0; layer < 2; ++layer) {
    // ================= GEMM1: hp = h @ w =================
    f32x4 acc[4][3];
#pragma unroll
    for (int rt = 0; rt < 4; ++rt)
#pragma unroll
      for (int ct = 0; ct < 3; ++ct)
        acc[rt][ct] = (f32x4){0.f, 0.f, 0.f, 0.f};

#pragma clang loop unroll(disable)
    for (int k0 = 0; k0 < DF; k0 += 32) {
      f16x8 bfr[3];
#pragma unroll
      for (int ct = 0; ct < 3; ++ct)
        bfr[ct] = *(const f16x8*)(wp + (size_t)(ct * 16) * DF + k0);
      f16x8 af[4];
#pragma unroll
      for (int rt = 0; rt < 4; ++rt)
        af[rt] = *(const f16x8*)&Hbuf[(rt * 16 + l16) * LDH + k0 + quad * 8];
#pragma unroll
      for (int rt = 0; rt < 4; ++rt)
#pragma unroll
        for (int ct = 0; ct < 3; ++ct)
          acc[rt][ct] = __builtin_amdgcn_mfma_f32_16x16x32_f16(af[rt], bfr[ct], acc[rt][ct], 0, 0, 0);
    }
    __syncthreads();   // all h reads done

    // write hp transposed: hpT[o][m]; C layout row=rt*16+quad*4+i, col=cb+ct*16+l16
#pragma unroll
    for (int rt = 0; rt < 4; ++rt)
#pragma unroll
      for (int ct = 0; ct < 3; ++ct) {
        int row0 = rt * 16 + quad * 4;
        int col  = cb + ct * 16 + l16;
        f16x4 h4 = {(f16)acc[rt][ct][0], (f16)acc[rt][ct][1],
                    (f16)acc[rt][ct][2], (f16)acc[rt][ct][3]};
        *(f16x4*)&Hbuf[col * LDT + row0] = h4;
      }
    __syncthreads();

    // ================= src/dst: th = tanh(hp), dot with a_src/a_dst =================
    {
      float s = 0.f, d = 0.f;
      int m = lane;
      int o0 = wv * 48;
      for (int o = o0; o < o0 + 48; ++o) {
        float t = tanh_fast((float)Hbuf[o * LDT + m]);
        s += t * asrcL[o];
        d += t * adstL[o];
      }
      redS[wv * 64 + m] = s;
      redD[wv * 64 + m] = d;
    }
    __syncthreads();
    if (tid < 64) {
      float s = 0.f, d = 0.f;
#pragma unroll
      for (int q = 0; q < 16; ++q) { s += redS[q * 64 + tid]; d += redD[q * 64 + tid]; }
      srcv[tid] = s;
      dstv[tid] = d;
    }
    __syncthreads();

    if (layer == 0) {
      // ---- full attention: wave wv does rows 4*wv..4*wv+3, lane = neighbor m ----
#pragma unroll
      for (int r = 0; r < 4; ++r) {
        int n = wv * 4 + r;
        float logit = srcv[n] + dstv[lane];
        logit = logit >= 0.f ? logit : NEG_SLOPE * logit;
        bool ok = (maskRow[n] >> lane) & 1ULL;
        float v = ok ? logit : -1e30f;
        float mx = v;
#pragma unroll
        for (int off = 32; off > 0; off >>= 1) mx = fmaxf(mx, __shfl_xor(mx, off, 64));
        float e = ok ? __expf(v - mx) : 0.f;
        float sm = e;
#pragma unroll
        for (int off = 32; off > 0; off >>= 1) sm += __shfl_xor(sm, off, 64);
        attnB[n * LDT + lane] = (f16)(e / sm);
      }
      __syncthreads();

      // ---- GEMM2: h_new = attn @ hp  (A=attnB row-major, B=hpT) ----
      f32x4 acc2[4][3];
#pragma unroll
      for (int rt = 0; rt < 4; ++rt)
#pragma unroll
        for (int ct = 0; ct < 3; ++ct)
          acc2[rt][ct] = (f32x4){0.f, 0.f, 0.f, 0.f};
#pragma unroll
      for (int k0 = 0; k0 < NN; k0 += 32) {
        f16x8 af2[4];
#pragma unroll
        for (int rt = 0; rt < 4; ++rt)
          af2[rt] = *(const f16x8*)&attnB[(rt * 16 + l16) * LDT + k0 + quad * 8];
#pragma unroll
        for (int ct = 0; ct < 3; ++ct) {
          f16x8 bf = *(const f16x8*)&Hbuf[(cb + ct * 16 + l16) * LDT + k0 + quad * 8];
#pragma unroll
          for (int rt = 0; rt < 4; ++rt)
            acc2[rt][ct] = __builtin_amdgcn_mfma_f32_16x16x32_f16(af2[rt], bf, acc2[rt][ct], 0, 0, 0);
        }
      }
      __syncthreads();  // all hpT reads done before overwriting Hbuf
      // h_new (+bias) -> Hbuf row-major (next layer's h)
#pragma unroll
      for (int rt = 0; rt < 4; ++rt)
#pragma unroll
        for (int ct = 0; ct < 3; ++ct)
#pragma unroll
          for (int i = 0; i < 4; ++i) {
            int row = rt * 16 + quad * 4 + i;
            int col = cb + ct * 16 + l16;
            Hbuf[row * LDH + col] = (f16)(acc2[rt][ct][i] + biasL[col]);
          }
      __syncthreads();
    } else {
      // ---- layer 2: only row 0 of h_new is ever used ----
      if (wv == 0) {
        float logit = srcv[0] + dstv[lane];
        logit = logit >= 0.f ? logit : NEG_SLOPE * logit;
        bool ok = (maskRow[0] >> lane) & 1ULL;
        float v = ok ? logit : -1e30f;
        float mx = v;
#pragma unroll
        for (int off = 32; off > 0; off >>= 1) mx = fmaxf(mx, __shfl_xor(mx, off, 64));
        float e = ok ? __expf(v - mx) : 0.f;
        float sm = e;
#pragma unroll
        for (int off = 32; off > 0; off >>= 1) sm += __shfl_xor(sm, off, 64);
        attn0[lane] = e / sm;   // keep fp32
      }
      __syncthreads();
      // h2_0[o] = bias[o] + sum_m attn0[m] * hpT[o][m]  (row o is 64 contiguous halves)
      if (tid < DF) {
        const int o = tid;
        const f16* rowp = &Hbuf[o * LDT];
        float a = biasL[o];
#pragma unroll
        for (int j = 0; j < 8; ++j) {
          f16x8 v = *(const f16x8*)&rowp[j * 8];
#pragma unroll
          for (int e = 0; e < 8; ++e) a += attn0[j * 8 + e] * (float)v[e];
        }
        h2row[o] = a;
      }
      __syncthreads();
      // l2norm of h2_0 -> cneighW
      float p = (tid < DF) ? h2row[tid] * h2row[tid] : 0.f;
#pragma unroll
      for (int off = 32; off > 0; off >>= 1) p += __shfl_xor(p, off, 64);
      if (lane == 0) ssqred[wv] = p;
      __syncthreads();
      if (tid == 0) {
        float ss = 0.f;
#pragma unroll
        for (int q = 0; q < 16; ++q) ss += ssqred[q];
        ssqred[0] = 1.0f / fmaxf(sqrtf(ss), 1e-12f);
      }
      __syncthreads();
      float scale = ssqred[0];
      if (tid < DF)
        cneighW[(size_t)b * DF + tid] = (f16)(h2row[tid] * scale);
    }
  }
}

// ---------- final: out = [center | cneigh] @ mlp_w.T + mlp_b, then row l2norm ----------
__global__ __launch_bounds__(512, 2) void final_mlp(
    const float* __restrict__ batch,
    const f16* __restrict__ cneighW,
    const f16* __restrict__ mwh,         // (768 x 1536) row-major (d, j)
    const float* __restrict__ mlp_b,
    float* __restrict__ out)
{
  __shared__ f16 Abuf[16 * LDT];   // 16 batch rows x 64-k chunk
  __shared__ float nrm[16];
  const int tid  = threadIdx.x;
  const int lane = tid & 63;
  const int wv   = tid >> 6;
  const int l16  = lane & 15;
  const int quad = lane >> 4;
  const int b0   = blockIdx.x * 16;
  const int cb   = wv * 96;

  f32x4 acc[6];
#pragma unroll
  for (int ct = 0; ct < 6; ++ct) acc[ct] = (f32x4){0.f, 0.f, 0.f, 0.f};

  for (int k0 = 0; k0 < 2 * DF; k0 += 64) {
    __syncthreads();
    // stage A chunk: 16 rows x 64 k (center fp32 or cneigh f16)
    for (int i = tid; i < 16 * 64; i += 512) {
      int r = i >> 6, c = i & 63;
      int j = k0 + c;
      float v;
      if (j < DF) v = batch[(size_t)(b0 + r) * (NN * DN) + j];        // node-0 features
      else        v = (float)cneighW[(size_t)(b0 + r) * DF + (j - DF)];
      Abuf[r * LDT + c] = (f16)v;
    }
    __syncthreads();
#pragma unroll
    for (int ks = 0; ks < 64; ks += 32) {
      f16x8 af = *(const f16x8*)&Abuf[l16 * LDT + ks + quad * 8];
#pragma unroll
      for (int ct = 0; ct < 6; ++ct) {
        f16x8 bf = *(const f16x8*)&mwh[(size_t)(cb + ct * 16 + l16) * (2 * DF) + k0 + ks + quad * 8];
        acc[ct] = __builtin_amdgcn_mfma_f32_16x16x32_f16(af, bf, acc[ct], 0, 0, 0);
      }
    }
  }
  if (tid < 16) nrm[tid] = 0.f;
  __syncthreads();
  float vals[6][4];
  float part[4] = {0.f, 0.f, 0.f, 0.f};
#pragma unroll
  for (int ct = 0; ct < 6; ++ct) {
    float bv = mlp_b[cb + ct * 16 + l16];
#pragma unroll
    for (int i = 0; i < 4; ++i) {
      float v = acc[ct][i] + bv;
      vals[ct][i] = v;
      part[i] += v * v;
    }
  }
#pragma unroll
  for (int i = 0; i < 4; ++i) {
    float p = part[i];
    p += __shfl_xor(p, 1, 64);
    p += __shfl_xor(p, 2, 64);
    p += __shfl_xor(p, 4, 64);
    p += __shfl_xor(p, 8, 64);
    if (l16 == 0) atomicAdd(&nrm[quad * 4 + i], p);
  }
  __syncthreads();
  float sc[4];
#pragma unroll
  for (int i = 0; i < 4; ++i) sc[i] = 1.0f / fmaxf(sqrtf(nrm[quad * 4 + i]), 1e-12f);
#pragma unroll
  for (int ct = 0; ct < 6; ++ct)
#pragma unroll
    for (int i = 0; i < 4; ++i) {
      int row = quad * 4 + i;
      int col = cb + ct * 16 + l16;
      out[(size_t)(b0 + row) * DF + col] = vals[ct][i] * sc[i];
    }
}

extern "C" void kernel_launch(void* const* d_in, const int* in_sizes, int n_in,
                              void* d_out, int out_size, void* d_ws, size_t ws_size,
                              hipStream_t stream) {
  const float* batch    = (const float*)d_in[0];  // (512, 64, 832)
  const float* w        = (const float*)d_in[1];  // (1, 768, 768)
  const float* a_src    = (const float*)d_in[2];  // (1, 768, 1)
  const float* a_dst    = (const float*)d_in[3];  // (1, 768, 1)
  const float* gat_bias = (const float*)d_in[4];  // (768,)
  const float* mlp_w    = (const float*)d_in[5];  // (768, 1536)
  const float* mlp_b    = (const float*)d_in[6];  // (768,)
  float* out = (float*)d_out;

  // workspace layout (f16): wT 768x768 | mlp_w 768x1536 | cneigh 512x768
  f16* wT      = (f16*)d_ws;
  f16* mwh     = wT + (size_t)DF * DF;
  f16* cneighW = mwh + (size_t)DF * 2 * DF;

  prep_wT<<<dim3(24 * 24), dim3(256), 0, stream>>>(w, wT);
  prep_mlp<<<dim3((DF * 2 * DF) / 256), dim3(256), 0, stream>>>(mlp_w, mwh);
  gat_fused<<<dim3(512), dim3(1024), 0, stream>>>(batch, wT, a_src, a_dst, gat_bias, cneighW);
  final_mlp<<<dim3(32), dim3(512), 0, stream>>>(batch, cneighW, mwh, mlp_b, out);
}

// Round 5
// 379.409 us; speedup vs baseline: 1.9732x; 1.1970x over previous
//
#include <hip/hip_runtime.h>
#include <math.h>

#define DF 768      // feature dim
#define NN 64       // nodes
#define DN 832      // batch row stride (D + N)
#define LDH 776     // h row-major LDS row stride (halves)
#define LDT 72      // hpT / attn LDS row stride (halves)
#define LDA 1540    // final_mlp A-tile row stride (halves): 770 dwords % 32 == 2 -> ~2-way (free)
#define NEG_SLOPE 0.2f

typedef _Float16 f16;
typedef __attribute__((ext_vector_type(4))) _Float16 f16x4;
typedef __attribute__((ext_vector_type(8))) _Float16 f16x8;
typedef __attribute__((ext_vector_type(4))) float f32x4;

__device__ __forceinline__ float tanh_fast(float x) {
  return 1.0f - 2.0f / (__expf(2.0f * x) + 1.0f);
}

// ---------- prep: transpose w (768x768 fp32) -> wT[o][k] f16 ----------
__global__ void prep_wT(const float* __restrict__ w, f16* __restrict__ wT) {
  __shared__ float tile[32][33];
  int bx = blockIdx.x % 24;   // o tile
  int by = blockIdx.x / 24;   // k tile
  int tx = threadIdx.x & 31;
  int ty = threadIdx.x >> 5;  // 0..7
#pragma unroll
  for (int rr = 0; rr < 4; ++rr)
    tile[ty + rr * 8][tx] = w[(size_t)(by * 32 + ty + rr * 8) * DF + bx * 32 + tx];
  __syncthreads();
#pragma unroll
  for (int rr = 0; rr < 4; ++rr)
    wT[(size_t)(bx * 32 + ty + rr * 8) * DF + by * 32 + tx] = (f16)tile[tx][ty + rr * 8];
}

// ---------- prep: mlp_w fp32 -> f16 ----------
__global__ void prep_mlp(const float* __restrict__ mw, f16* __restrict__ mwh) {
  int i = blockIdx.x * 256 + threadIdx.x;
  mwh[i] = (f16)mw[i];
}

// ---------- fused 2-layer GAT: one workgroup (1024 thr, 16 waves) per batch item ----------
// R4: 64 arch + 48 acc = 112/128 budget, no spill, 239 us, MfmaUtil 14% ->
// latency-bound on the serial per-iter chain (3 wT loads -> vmcnt(0) -> MFMA).
// R5: restore bnx prefetch within the known budget (bfr12+bnx12+af16+addr~15
// + acc48 ~= 123 <= 128). unroll(disable) kept so the unroller can't widen
// live ranges. Tripwire: WRITE_SIZE ballooning == spill cliff -> revert.
__global__ __launch_bounds__(1024, 4) void gat_fused(
    const float* __restrict__ batch,
    const f16* __restrict__ wT,          // (768 x 768), wT[o][k] = w[k][o]
    const float* __restrict__ a_src,
    const float* __restrict__ a_dst,
    const float* __restrict__ gat_bias,
    f16* __restrict__ cneighW)           // (512 x 768) l2normed h[:,0]
{
  // Hbuf doubles as: h row-major (64 x LDH) and hpT (768 x LDT)
  __shared__ __align__(16) f16 Hbuf[DF * LDT];   // 110592 B
  __shared__ __align__(16) f16 attnB[NN * LDT];  // 9216 B
  __shared__ float asrcL[DF], adstL[DF], biasL[DF];
  __shared__ float srcv[NN], dstv[NN];
  __shared__ float redS[16 * NN], redD[16 * NN];
  __shared__ unsigned long long maskRow[NN];
  __shared__ float attn0[NN];
  __shared__ float h2row[DF];
  __shared__ float ssqred[16];

  const int tid  = threadIdx.x;
  const int lane = tid & 63;
  const int wv   = tid >> 6;     // wave 0..15
  const int l16  = lane & 15;
  const int quad = lane >> 4;    // 0..3
  const int b    = blockIdx.x;
  const int cb   = wv * 48;      // this wave's column base (16 waves x 48 = 768)

  const float* bb = batch + (size_t)b * (NN * DN);

  // params -> LDS
  for (int i = tid; i < DF; i += 1024) {
    asrcL[i] = a_src[i];
    adstL[i] = a_dst[i];
    biasL[i] = gat_bias[i];
  }
  // stage h0 = features (fp32 -> f16), row-major, float4-vectorized
  for (int i = tid; i < NN * (DF / 4); i += 1024) {
    int r = i / (DF / 4), c4 = i - r * (DF / 4);
    float4 v = *(const float4*)&bb[r * DN + c4 * 4];
    f16x4 h4 = {(f16)v.x, (f16)v.y, (f16)v.z, (f16)v.w};
    *(f16x4*)&Hbuf[r * LDH + c4 * 4] = h4;
  }
  // adjacency mask via ballot: wave wv builds rows 4*wv..4*wv+3
#pragma unroll
  for (int r = 0; r < 4; ++r) {
    int n = wv * 4 + r;
    float av = bb[n * DN + DF + lane];
    unsigned long long m = __ballot(av != 0.0f);
    if (lane == 0) maskRow[n] = m | (1ULL << n);   // eye
  }
  __syncthreads();

  // per-wave wT base: columns cb+ct*16+l16, k offset quad*8
  const f16* wp = wT + (size_t)(cb + l16) * DF + quad * 8;

  for (int layer = 0; layer < 2; ++layer) {
    // ================= GEMM1: hp = h @ w =================
    f32x4 acc[4][3];
#pragma unroll
    for (int rt = 0; rt < 4; ++rt)
#pragma unroll
      for (int ct = 0; ct < 3; ++ct)
        acc[rt][ct] = (f32x4){0.f, 0.f, 0.f, 0.f};

    // software-pipelined B fragments: bfr = current, bnx = next k-step
    f16x8 bfr[3], bnx[3];
#pragma unroll
    for (int ct = 0; ct < 3; ++ct)
      bfr[ct] = *(const f16x8*)(wp + (size_t)(ct * 16) * DF);

#pragma clang loop unroll(disable)
    for (int k0 = 0; k0 < DF; k0 += 32) {
      int kn = (k0 + 32 < DF) ? (k0 + 32) : 0;   // wrap: last prefetch harmless
#pragma unroll
      for (int ct = 0; ct < 3; ++ct)
        bnx[ct] = *(const f16x8*)(wp + (size_t)(ct * 16) * DF + kn);
      f16x8 af[4];
#pragma unroll
      for (int rt = 0; rt < 4; ++rt)
        af[rt] = *(const f16x8*)&Hbuf[(rt * 16 + l16) * LDH + k0 + quad * 8];
#pragma unroll
      for (int rt = 0; rt < 4; ++rt)
#pragma unroll
        for (int ct = 0; ct < 3; ++ct)
          acc[rt][ct] = __builtin_amdgcn_mfma_f32_16x16x32_f16(af[rt], bfr[ct], acc[rt][ct], 0, 0, 0);
#pragma unroll
      for (int ct = 0; ct < 3; ++ct) bfr[ct] = bnx[ct];
    }
    __syncthreads();   // all h reads done

    // write hp transposed: hpT[o][m]; C layout row=rt*16+quad*4+i, col=cb+ct*16+l16
#pragma unroll
    for (int rt = 0; rt < 4; ++rt)
#pragma unroll
      for (int ct = 0; ct < 3; ++ct) {
        int row0 = rt * 16 + quad * 4;
        int col  = cb + ct * 16 + l16;
        f16x4 h4 = {(f16)acc[rt][ct][0], (f16)acc[rt][ct][1],
                    (f16)acc[rt][ct][2], (f16)acc[rt][ct][3]};
        *(f16x4*)&Hbuf[col * LDT + row0] = h4;
      }
    __syncthreads();

    // ================= src/dst: th = tanh(hp), dot with a_src/a_dst =================
    {
      float s = 0.f, d = 0.f;
      int m = lane;
      int o0 = wv * 48;
      for (int o = o0; o < o0 + 48; ++o) {
        float t = tanh_fast((float)Hbuf[o * LDT + m]);
        s += t * asrcL[o];
        d += t * adstL[o];
      }
      redS[wv * 64 + m] = s;
      redD[wv * 64 + m] = d;
    }
    __syncthreads();
    if (tid < 64) {
      float s = 0.f, d = 0.f;
#pragma unroll
      for (int q = 0; q < 16; ++q) { s += redS[q * 64 + tid]; d += redD[q * 64 + tid]; }
      srcv[tid] = s;
      dstv[tid] = d;
    }
    __syncthreads();

    if (layer == 0) {
      // ---- full attention: wave wv does rows 4*wv..4*wv+3, lane = neighbor m ----
#pragma unroll
      for (int r = 0; r < 4; ++r) {
        int n = wv * 4 + r;
        float logit = srcv[n] + dstv[lane];
        logit = logit >= 0.f ? logit : NEG_SLOPE * logit;
        bool ok = (maskRow[n] >> lane) & 1ULL;
        float v = ok ? logit : -1e30f;
        float mx = v;
#pragma unroll
        for (int off = 32; off > 0; off >>= 1) mx = fmaxf(mx, __shfl_xor(mx, off, 64));
        float e = ok ? __expf(v - mx) : 0.f;
        float sm = e;
#pragma unroll
        for (int off = 32; off > 0; off >>= 1) sm += __shfl_xor(sm, off, 64);
        attnB[n * LDT + lane] = (f16)(e / sm);
      }
      __syncthreads();

      // ---- GEMM2: h_new = attn @ hp  (A=attnB row-major, B=hpT) ----
      f32x4 acc2[4][3];
#pragma unroll
      for (int rt = 0; rt < 4; ++rt)
#pragma unroll
        for (int ct = 0; ct < 3; ++ct)
          acc2[rt][ct] = (f32x4){0.f, 0.f, 0.f, 0.f};
#pragma unroll
      for (int k0 = 0; k0 < NN; k0 += 32) {
        f16x8 af2[4];
#pragma unroll
        for (int rt = 0; rt < 4; ++rt)
          af2[rt] = *(const f16x8*)&attnB[(rt * 16 + l16) * LDT + k0 + quad * 8];
#pragma unroll
        for (int ct = 0; ct < 3; ++ct) {
          f16x8 bf = *(const f16x8*)&Hbuf[(cb + ct * 16 + l16) * LDT + k0 + quad * 8];
#pragma unroll
          for (int rt = 0; rt < 4; ++rt)
            acc2[rt][ct] = __builtin_amdgcn_mfma_f32_16x16x32_f16(af2[rt], bf, acc2[rt][ct], 0, 0, 0);
        }
      }
      __syncthreads();  // all hpT reads done before overwriting Hbuf
      // h_new (+bias) -> Hbuf row-major (next layer's h)
#pragma unroll
      for (int rt = 0; rt < 4; ++rt)
#pragma unroll
        for (int ct = 0; ct < 3; ++ct)
#pragma unroll
          for (int i = 0; i < 4; ++i) {
            int row = rt * 16 + quad * 4 + i;
            int col = cb + ct * 16 + l16;
            Hbuf[row * LDH + col] = (f16)(acc2[rt][ct][i] + biasL[col]);
          }
      __syncthreads();
    } else {
      // ---- layer 2: only row 0 of h_new is ever used ----
      if (wv == 0) {
        float logit = srcv[0] + dstv[lane];
        logit = logit >= 0.f ? logit : NEG_SLOPE * logit;
        bool ok = (maskRow[0] >> lane) & 1ULL;
        float v = ok ? logit : -1e30f;
        float mx = v;
#pragma unroll
        for (int off = 32; off > 0; off >>= 1) mx = fmaxf(mx, __shfl_xor(mx, off, 64));
        float e = ok ? __expf(v - mx) : 0.f;
        float sm = e;
#pragma unroll
        for (int off = 32; off > 0; off >>= 1) sm += __shfl_xor(sm, off, 64);
        attn0[lane] = e / sm;   // keep fp32
      }
      __syncthreads();
      // h2_0[o] = bias[o] + sum_m attn0[m] * hpT[o][m]  (row o is 64 contiguous halves)
      if (tid < DF) {
        const int o = tid;
        const f16* rowp = &Hbuf[o * LDT];
        float a = biasL[o];
#pragma unroll
        for (int j = 0; j < 8; ++j) {
          f16x8 v = *(const f16x8*)&rowp[j * 8];
#pragma unroll
          for (int e = 0; e < 8; ++e) a += attn0[j * 8 + e] * (float)v[e];
        }
        h2row[o] = a;
      }
      __syncthreads();
      // l2norm of h2_0 -> cneighW
      float p = (tid < DF) ? h2row[tid] * h2row[tid] : 0.f;
#pragma unroll
      for (int off = 32; off > 0; off >>= 1) p += __shfl_xor(p, off, 64);
      if (lane == 0) ssqred[wv] = p;
      __syncthreads();
      if (tid == 0) {
        float ss = 0.f;
#pragma unroll
        for (int q = 0; q < 16; ++q) ss += ssqred[q];
        ssqred[0] = 1.0f / fmaxf(sqrtf(ss), 1e-12f);
      }
      __syncthreads();
      float scale = ssqred[0];
      if (tid < DF)
        cneighW[(size_t)b * DF + tid] = (f16)(h2row[tid] * scale);
    }
  }
}

// ---------- final MLP GEMM: grid (32 M-tiles, 6 N-chunks), 256 thr ----------
// R4's final_mlp had only 32 WGs (12.5% of CUs) and a serial 24-chunk K-loop.
// Now: A-tile (16 rows x 1536 k, 48 KB) staged ONCE, B prefetched, 192 WGs.
// Writes raw (pre-l2norm) out; l2norm_rows finishes.
__global__ __launch_bounds__(256) void final_mlp(
    const float* __restrict__ batch,
    const f16* __restrict__ cneighW,
    const f16* __restrict__ mwh,         // (768 x 1536) row-major (d, j)
    const float* __restrict__ mlp_b,
    float* __restrict__ out)
{
  __shared__ __align__(16) f16 Abuf[16 * LDA];   // 49280 B
  const int tid  = threadIdx.x;
  const int lane = tid & 63;
  const int wv   = tid >> 6;          // 0..3
  const int l16  = lane & 15;
  const int quad = lane >> 4;
  const int b0   = blockIdx.x * 16;   // batch-row tile
  const int cb   = blockIdx.y * 128 + wv * 32;  // column base (2 ct of 16)

  // stage A: 16 rows x 1536 halves; j<768 from batch node-0 (fp32), else cneigh (f16)
  for (int i = tid; i < 16 * 384; i += 256) {
    int r = i / 384, c4 = i - r * 384;
    int j = c4 * 4;
    f16x4 h4;
    if (j < DF) {
      float4 v = *(const float4*)&batch[(size_t)(b0 + r) * (NN * DN) + j];
      h4 = (f16x4){(f16)v.x, (f16)v.y, (f16)v.z, (f16)v.w};
    } else {
      h4 = *(const f16x4*)&cneighW[(size_t)(b0 + r) * DF + (j - DF)];
    }
    *(f16x4*)&Abuf[r * LDA + j] = h4;
  }
  __syncthreads();

  f32x4 acc[2];
  acc[0] = (f32x4){0.f, 0.f, 0.f, 0.f};
  acc[1] = (f32x4){0.f, 0.f, 0.f, 0.f};

  const f16* mp = mwh + (size_t)(cb + l16) * (2 * DF) + quad * 8;
  f16x8 bfr[2], bnx[2];
  bfr[0] = *(const f16x8*)(mp);
  bfr[1] = *(const f16x8*)(mp + (size_t)16 * (2 * DF));

#pragma clang loop unroll(disable)
  for (int k0 = 0; k0 < 2 * DF; k0 += 32) {
    int kn = (k0 + 32 < 2 * DF) ? (k0 + 32) : 0;
    bnx[0] = *(const f16x8*)(mp + kn);
    bnx[1] = *(const f16x8*)(mp + (size_t)16 * (2 * DF) + kn);
    // af: two b64 reads (LDA stride keeps banks ~conflict-free)
    f16x4 a0 = *(const f16x4*)&Abuf[l16 * LDA + k0 + quad * 8];
    f16x4 a1 = *(const f16x4*)&Abuf[l16 * LDA + k0 + quad * 8 + 4];
    f16x8 af = {a0[0], a0[1], a0[2], a0[3], a1[0], a1[1], a1[2], a1[3]};
    acc[0] = __builtin_amdgcn_mfma_f32_16x16x32_f16(af, bfr[0], acc[0], 0, 0, 0);
    acc[1] = __builtin_amdgcn_mfma_f32_16x16x32_f16(af, bfr[1], acc[1], 0, 0, 0);
    bfr[0] = bnx[0];
    bfr[1] = bnx[1];
  }

  // epilogue: + bias, store raw (l2norm_rows normalizes)
#pragma unroll
  for (int ct = 0; ct < 2; ++ct) {
    int col = cb + ct * 16 + l16;
    float bv = mlp_b[col];
#pragma unroll
    for (int i = 0; i < 4; ++i) {
      int row = quad * 4 + i;
      out[(size_t)(b0 + row) * DF + col] = acc[ct][i] + bv;
    }
  }
}

// ---------- per-row l2 normalization of out (512 x 768 fp32) ----------
__global__ __launch_bounds__(256) void l2norm_rows(float* __restrict__ out) {
  const int lane = threadIdx.x & 63;
  const int wv   = threadIdx.x >> 6;
  const int row  = blockIdx.x * 4 + wv;
  float* rp = out + (size_t)row * DF;
  float v[12];
  float ss = 0.f;
#pragma unroll
  for (int j = 0; j < 12; ++j) {
    v[j] = rp[j * 64 + lane];
    ss += v[j] * v[j];
  }
#pragma unroll
  for (int off = 32; off > 0; off >>= 1) ss += __shfl_xor(ss, off, 64);
  float sc = 1.0f / fmaxf(sqrtf(ss), 1e-12f);
#pragma unroll
  for (int j = 0; j < 12; ++j) rp[j * 64 + lane] = v[j] * sc;
}

extern "C" void kernel_launch(void* const* d_in, const int* in_sizes, int n_in,
                              void* d_out, int out_size, void* d_ws, size_t ws_size,
                              hipStream_t stream) {
  const float* batch    = (const float*)d_in[0];  // (512, 64, 832)
  const float* w        = (const float*)d_in[1];  // (1, 768, 768)
  const float* a_src    = (const float*)d_in[2];  // (1, 768, 1)
  const float* a_dst    = (const float*)d_in[3];  // (1, 768, 1)
  const float* gat_bias = (const float*)d_in[4];  // (768,)
  const float* mlp_w    = (const float*)d_in[5];  // (768, 1536)
  const float* mlp_b    = (const float*)d_in[6];  // (768,)
  float* out = (float*)d_out;

  // workspace layout (f16): wT 768x768 | mlp_w 768x1536 | cneigh 512x768
  f16* wT      = (f16*)d_ws;
  f16* mwh     = wT + (size_t)DF * DF;
  f16* cneighW = mwh + (size_t)DF * 2 * DF;

  prep_wT<<<dim3(24 * 24), dim3(256), 0, stream>>>(w, wT);
  prep_mlp<<<dim3((DF * 2 * DF) / 256), dim3(256), 0, stream>>>(mlp_w, mwh);
  gat_fused<<<dim3(512), dim3(1024), 0, stream>>>(batch, wT, a_src, a_dst, gat_bias, cneighW);
  final_mlp<<<dim3(32, 6), dim3(256), 0, stream>>>(batch, cneighW, mwh, mlp_b, out);
  l2norm_rows<<<dim3(128), dim3(256), 0, stream>>>(out);
}